// Round 9
// baseline (436.488 us; speedup 1.0000x reference)
//
#include <hip/hip_runtime.h>
#include <hip/hip_fp16.h>
#include <math.h>

#define N_NODES 100000
#define N_EDGES 600000
#define HIDDEN 128
#define EDGE_CH 4
#define NUM_LAYERS 3
#define MLP_ROWS 64   // nodes per block in fp32 fallback mlp_kernel

#define SCAN_BLOCK 256
#define SCAN_GRID ((N_NODES + SCAN_BLOCK - 1) / SCAN_BLOCK)   // 391

#define TSTR 68             // padded LDS row stride (floats), half-width transpose
#define MLP5_TILES ((N_NODES + 255) / 256)   // 391 (256 nodes per 16-wave block)
#define MLP5_GRID 256       // 1 block/CU (LDS-bound), grid-stride over tiles

// setup_kernel block ranges
#define EMB_BLOCKS ((N_NODES * 32) / 256)    // 12500
#define ZB_BLOCKS  ((N_NODES + 255) / 256)   // 391
#define WP_BLOCKS  ((NUM_LAYERS * 2 * HIDDEN * HIDDEN) / 256)  // 384

typedef short bf16x8 __attribute__((ext_vector_type(8)));
typedef float f32x4  __attribute__((ext_vector_type(4)));

__device__ inline unsigned short f2bf(float x) {           // RNE fp32 -> bf16 bits
    unsigned u = __float_as_uint(x);
    return (unsigned short)((u + 0x7fff + ((u >> 16) & 1)) >> 16);
}
__device__ inline float bf2f(unsigned short b) { return __uint_as_float(((unsigned)b) << 16); }

__device__ inline float4 h8tof4(uint2 u) {                 // 4 packed halves -> float4
    __half2 a = *reinterpret_cast<const __half2*>(&u.x);
    __half2 b = *reinterpret_cast<const __half2*>(&u.y);
    float2 fa = __half22float2(a);
    float2 fb = __half22float2(b);
    return make_float4(fa.x, fa.y, fb.x, fb.y);
}
__device__ inline uint2 f4toh8(float4 v) {                 // float4 -> 4 packed halves
    __half2 a = __floats2half2_rn(v.x, v.y);
    __half2 b = __floats2half2_rn(v.z, v.w);
    uint2 u;
    u.x = *reinterpret_cast<unsigned*>(&a);
    u.y = *reinterpret_cast<unsigned*>(&b);
    return u;
}

// packed relu: max(x, 0) on 2 halves via v_pk_max_f16 (no __hmax2 in ROCm 7.2)
__device__ inline __half2 pkmax0(__half2 a) {
    unsigned ua = *reinterpret_cast<unsigned*>(&a);
    unsigned r;
    asm("v_pk_max_f16 %0, %1, %2" : "=v"(r) : "v"(ua), "v"(0u));
    return *reinterpret_cast<__half2*>(&r);
}

// ---------------- fused setup: embed + zero(pos) + batch_out + wprep ----------------

__global__ void setup_kernel(const float* __restrict__ emb,
                             const int* __restrict__ z,
                             float* __restrict__ x,
                             __half* __restrict__ xh,
                             int write_xh, int write_x,
                             int* __restrict__ pos,
                             const int* __restrict__ bv,
                             float* __restrict__ out,
                             const float* __restrict__ W1,
                             const float* __restrict__ W2,
                             unsigned short* __restrict__ wt,
                             int do_wprep) {
    int b = blockIdx.x;
    if (b < EMB_BLOCKS) {
        int t = b * 256 + threadIdx.x;
        int node = t >> 5;
        int c4 = t & 31;
        if (node < N_NODES) {
            float4 v = ((const float4*)(emb + (size_t)z[node] * HIDDEN))[c4];
            if (write_x)
                ((float4*)(x + (size_t)node * HIDDEN))[c4] = v;
            if (write_xh)
                ((uint2*)(xh + (size_t)node * HIDDEN))[c4] = f4toh8(v);
        }
    } else if (b < EMB_BLOCKS + ZB_BLOCKS) {
        int i = (b - EMB_BLOCKS) * 256 + threadIdx.x;
        if (i < N_NODES) {
            pos[i] = 0;
            out[i] = (float)bv[i];
        }
    } else if (do_wprep) {
        int idx = (b - EMB_BLOCKS - ZB_BLOCKS) * 256 + threadIdx.x;
        if (idx < NUM_LAYERS * 2 * HIDDEN * HIDDEN) {
            int j    = idx & 7;
            int lane = (idx >> 3) & 63;
            int ks   = (idx >> 9) & 3;
            int nt   = (idx >> 11) & 7;
            int mat  = (idx >> 14) & 1;
            int l    = idx >> 15;
            int n = nt * 16 + (lane & 15);
            int k = ks * 32 + (lane >> 4) * 8 + j;
            const float* W = mat ? W2 : W1;
            wt[idx] = f2bf(W[(size_t)l * HIDDEN * HIDDEN + (size_t)k * HIDDEN + n]);
        }
    }
}

// ---------------- common kernels (fallback paths) ----------------

__global__ void embed_init_kernel(const float* __restrict__ emb,
                                  const int* __restrict__ z,
                                  float* __restrict__ x,
                                  float* __restrict__ agg,
                                  int write_agg,
                                  __half* __restrict__ xh,
                                  int write_xh,
                                  int write_x) {
    int t = blockIdx.x * blockDim.x + threadIdx.x;
    int node = t >> 5;
    int c4 = t & 31;
    if (node < N_NODES) {
        float4 v = ((const float4*)(emb + (size_t)z[node] * HIDDEN))[c4];
        if (write_x)
            ((float4*)(x + (size_t)node * HIDDEN))[c4] = v;
        if (write_agg)
            ((float4*)(agg + (size_t)node * HIDDEN))[c4] = v;
        if (write_xh)
            ((uint2*)(xh + (size_t)node * HIDDEN))[c4] = f4toh8(v);
    }
}

// MFMA MLP v5: 1024 threads / 16 waves per block -> 4 waves/SIMD.
// Both weight images in LDS (64 KB); half-width (TSTR=68) wave-private
// transpose buffers (69.6 KB) -> 133.6 KB total, 1 block/CU. GEMM2 is
// ks-interleaved through the half-width buffer. No block barriers in the
// main loop. A = exact input as bf16 hi+lo (2 MFMAs per fragment).
__global__ __launch_bounds__(1024, 1) void mlp_mfma5_kernel(
        const void* __restrict__ hbuf,
        int h_half,
        const unsigned short* __restrict__ wfrag,  // this layer's [2][8][4][64][8] image
        const float* __restrict__ b1, const float* __restrict__ b2,
        float* __restrict__ x,
        __half* __restrict__ xh,
        int write_x, int write_xh) {
    __shared__ short wlds[2 * 16384];              // 64 KB: both matrices, fragment order
    __shared__ float tbuf[16 * 16 * TSTR];         // 69.6 KB: per-wave half-width buffers
    int tid   = threadIdx.x;
    int wave  = tid >> 6;
    int lane  = tid & 63;
    int row16 = lane & 15;
    int quad  = lane >> 4;
    float* myt = tbuf + wave * 16 * TSTR;

    // stage both weight images linearly (4096 float4)
    for (int i = tid; i < 4096; i += 1024)
        ((float4*)wlds)[i] = ((const float4*)wfrag)[i];
    __syncthreads();                               // only barrier in the kernel

    // per-lane biases (column = nt*16+row16), hoisted out of the tile loop
    float bias1[8], bias2[8];
    #pragma unroll
    for (int nt = 0; nt < 8; nt++) {
        bias1[nt] = b1[nt * 16 + row16];
        bias2[nt] = b2[nt * 16 + row16];
    }

    for (int tile = blockIdx.x; tile < MLP5_TILES; tile += gridDim.x) {
        int wnode0 = tile * 256 + wave * 16;
        int mnode  = wnode0 + row16;
        bool valid = (mnode < N_NODES);
        int srcnode = valid ? mnode : 0;

        // ---- A1 fragments straight from global h (fp16 or fp32) ----
        bf16x8 ahi[4], alo[4];
        if (h_half) {
            const __half* hrow = (const __half*)hbuf + (size_t)srcnode * HIDDEN + quad * 8;
            #pragma unroll
            for (int ks = 0; ks < 4; ks++) {
                float v[8];
                if (valid) {
                    uint4 u = *(const uint4*)(hrow + ks * 32);   // 8 halves, 16 B
                    const __half2* hp = reinterpret_cast<const __half2*>(&u);
                    float2 f0 = __half22float2(hp[0]);
                    float2 f1 = __half22float2(hp[1]);
                    float2 f2 = __half22float2(hp[2]);
                    float2 f3 = __half22float2(hp[3]);
                    v[0]=f0.x; v[1]=f0.y; v[2]=f1.x; v[3]=f1.y;
                    v[4]=f2.x; v[5]=f2.y; v[6]=f3.x; v[7]=f3.y;
                } else {
                    #pragma unroll
                    for (int j = 0; j < 8; j++) v[j] = 0.f;
                }
                bf16x8 hi, lo;
                #pragma unroll
                for (int j = 0; j < 8; j++) {
                    unsigned short hb = f2bf(v[j]);
                    hi[j] = (short)hb;
                    lo[j] = (short)f2bf(v[j] - bf2f(hb));
                }
                ahi[ks] = hi; alo[ks] = lo;
            }
        } else {
            const float* hrow = (const float*)hbuf + (size_t)srcnode * HIDDEN + quad * 8;
            #pragma unroll
            for (int ks = 0; ks < 4; ks++) {
                float v[8];
                *(float4*)(v + 0) = valid ? *(const float4*)(hrow + ks * 32 + 0) : make_float4(0.f,0.f,0.f,0.f);
                *(float4*)(v + 4) = valid ? *(const float4*)(hrow + ks * 32 + 4) : make_float4(0.f,0.f,0.f,0.f);
                bf16x8 hi, lo;
                #pragma unroll
                for (int j = 0; j < 8; j++) {
                    unsigned short hb = f2bf(v[j]);
                    hi[j] = (short)hb;
                    lo[j] = (short)f2bf(v[j] - bf2f(hb));
                }
                ahi[ks] = hi; alo[ks] = lo;
            }
        }

        // ---- GEMM1: B (W1) from LDS, 8 independent acc chains ----
        f32x4 acc1[8];
        #pragma unroll
        for (int nt = 0; nt < 8; nt++) acc1[nt] = (f32x4){0.f, 0.f, 0.f, 0.f};
        #pragma unroll
        for (int ks = 0; ks < 4; ks++) {
            #pragma unroll
            for (int nt = 0; nt < 8; nt++) {
                bf16x8 Bv = *(const bf16x8*)(wlds + (size_t)((nt * 4 + ks) * 64 + lane) * 8);
                acc1[nt] = __builtin_amdgcn_mfma_f32_16x16x32_bf16(ahi[ks], Bv, acc1[nt], 0, 0, 0);
                acc1[nt] = __builtin_amdgcn_mfma_f32_16x16x32_bf16(alo[ks], Bv, acc1[nt], 0, 0, 0);
            }
        }

        // ---- GEMM2, ks-interleaved through half-width wave-private buffer ----
        f32x4 acc2[8];
        #pragma unroll
        for (int nt = 0; nt < 8; nt++) acc2[nt] = (f32x4){0.f, 0.f, 0.f, 0.f};

        #pragma unroll
        for (int p = 0; p < 2; p++) {
            // bias + silu for 4 col-tiles -> wave-private LDS (cols 64p..64p+63)
            #pragma unroll
            for (int l4 = 0; l4 < 4; l4++) {
                int nt = p * 4 + l4;
                #pragma unroll
                for (int r = 0; r < 4; r++) {
                    float v = acc1[nt][r] + bias1[nt];
                    v = v / (1.f + __expf(-v));
                    myt[(quad * 4 + r) * TSTR + l4 * 16 + row16] = v;
                }
            }
            // wave-synchronous: same wave reads below; lgkmcnt ordering suffices

            // A2 fragments for ks = 2p, 2p+1
            bf16x8 a2hi[2], a2lo[2];
            #pragma unroll
            for (int kk = 0; kk < 2; kk++) {
                const float* pp = myt + row16 * TSTR + kk * 32 + quad * 8;
                float v[8];
                *(float4*)(v + 0) = *(const float4*)(pp + 0);
                *(float4*)(v + 4) = *(const float4*)(pp + 4);
                bf16x8 hi, lo;
                #pragma unroll
                for (int j = 0; j < 8; j++) {
                    unsigned short hb = f2bf(v[j]);
                    hi[j] = (short)hb;
                    lo[j] = (short)f2bf(v[j] - bf2f(hb));
                }
                a2hi[kk] = hi; a2lo[kk] = lo;
            }

            // partial GEMM2 with B (W2) from LDS
            #pragma unroll
            for (int kk = 0; kk < 2; kk++) {
                int ks = p * 2 + kk;
                #pragma unroll
                for (int nt = 0; nt < 8; nt++) {
                    bf16x8 Bv = *(const bf16x8*)(wlds + (size_t)(16384 + ((nt * 4 + ks) * 64 + lane) * 8));
                    acc2[nt] = __builtin_amdgcn_mfma_f32_16x16x32_bf16(a2hi[kk], Bv, acc2[nt], 0, 0, 0);
                    acc2[nt] = __builtin_amdgcn_mfma_f32_16x16x32_bf16(a2lo[kk], Bv, acc2[nt], 0, 0, 0);
                }
            }
        }

        // ---- epilogue: transpose through LDS, coalesced >=64B/lane stores ----
        int onode = wnode0 + row16;
        if (write_xh) {
            // full-width fp16 transpose reusing the f32 buffer (stride 136 halves)
            __half* hmyt = (__half*)myt;
            #pragma unroll
            for (int nt = 0; nt < 8; nt++) {
                #pragma unroll
                for (int r = 0; r < 4; r++)
                    hmyt[(quad * 4 + r) * 136 + nt * 16 + row16] =
                        __float2half_rn(acc2[nt][r] + bias2[nt]);
            }
            if (onode < N_NODES) {
                const uint4* pr = (const uint4*)(hmyt + row16 * 136 + quad * 32);
                uint4* orow = (uint4*)(xh + (size_t)onode * HIDDEN + quad * 32);
                #pragma unroll
                for (int j = 0; j < 4; j++) orow[j] = pr[j];
            }
        }
        if (write_x) {
            // two half-width fp32 passes
            #pragma unroll
            for (int p = 0; p < 2; p++) {
                #pragma unroll
                for (int l4 = 0; l4 < 4; l4++) {
                    int nt = p * 4 + l4;
                    #pragma unroll
                    for (int r = 0; r < 4; r++)
                        myt[(quad * 4 + r) * TSTR + l4 * 16 + row16] = acc2[nt][r] + bias2[nt];
                }
                if (onode < N_NODES) {
                    const float* prow = myt + row16 * TSTR + quad * 16;
                    float* orow = x + (size_t)onode * HIDDEN + p * 64 + quad * 16;
                    #pragma unroll
                    for (int j = 0; j < 4; j++)
                        *(float4*)(orow + 4 * j) = *(const float4*)(prow + 4 * j);
                }
            }
        }
    }
}

// fp32 fallback MLP
__global__ void mlp_kernel(const float* __restrict__ h,
                           const float* __restrict__ W1, const float* __restrict__ b1,
                           const float* __restrict__ W2, const float* __restrict__ b2,
                           float* __restrict__ x) {
    __shared__ float hs[MLP_ROWS * HIDDEN];
    int rg = threadIdx.x >> 5;
    int c4 = threadIdx.x & 31;
    int node0 = blockIdx.x * MLP_ROWS;

    for (int i = threadIdx.x; i < MLP_ROWS * 32; i += 256) {
        int node = node0 + (i >> 5);
        float4 v = (node < N_NODES)
                 ? ((const float4*)(h + (size_t)node * HIDDEN))[i & 31]
                 : make_float4(0.f, 0.f, 0.f, 0.f);
        ((float4*)hs)[i] = v;
    }
    __syncthreads();

    float4 acc[8];
    {
        float4 bv = ((const float4*)b1)[c4];
        #pragma unroll
        for (int r = 0; r < 8; r++) acc[r] = bv;
    }
    const float* hbase = hs + rg * 8 * HIDDEN;

    for (int k4 = 0; k4 < HIDDEN; k4 += 4) {
        float4 w0 = ((const float4*)(W1 + (size_t)(k4 + 0) * HIDDEN))[c4];
        float4 w1 = ((const float4*)(W1 + (size_t)(k4 + 1) * HIDDEN))[c4];
        float4 w2 = ((const float4*)(W1 + (size_t)(k4 + 2) * HIDDEN))[c4];
        float4 w3 = ((const float4*)(W1 + (size_t)(k4 + 3) * HIDDEN))[c4];
        #pragma unroll
        for (int r = 0; r < 8; r++) {
            float4 hv = *(const float4*)(hbase + r * HIDDEN + k4);
            acc[r].x += hv.x*w0.x + hv.y*w1.x + hv.z*w2.x + hv.w*w3.x;
            acc[r].y += hv.x*w0.y + hv.y*w1.y + hv.z*w2.y + hv.w*w3.y;
            acc[r].z += hv.x*w0.z + hv.y*w1.z + hv.z*w2.z + hv.w*w3.z;
            acc[r].w += hv.x*w0.w + hv.y*w1.w + hv.z*w2.w + hv.w*w3.w;
        }
    }

    __syncthreads();
    #pragma unroll
    for (int r = 0; r < 8; r++) {
        float4 a = acc[r];
        a.x = a.x / (1.f + __expf(-a.x));
        a.y = a.y / (1.f + __expf(-a.y));
        a.z = a.z / (1.f + __expf(-a.z));
        a.w = a.w / (1.f + __expf(-a.w));
        *(float4*)(hs + (rg * 8 + r) * HIDDEN + c4 * 4) = a;
    }
    __syncthreads();

    {
        float4 bv = ((const float4*)b2)[c4];
        #pragma unroll
        for (int r = 0; r < 8; r++) acc[r] = bv;
    }
    for (int k4 = 0; k4 < HIDDEN; k4 += 4) {
        float4 w0 = ((const float4*)(W2 + (size_t)(k4 + 0) * HIDDEN))[c4];
        float4 w1 = ((const float4*)(W2 + (size_t)(k4 + 1) * HIDDEN))[c4];
        float4 w2 = ((const float4*)(W2 + (size_t)(k4 + 2) * HIDDEN))[c4];
        float4 w3 = ((const float4*)(W2 + (size_t)(k4 + 3) * HIDDEN))[c4];
        #pragma unroll
        for (int r = 0; r < 8; r++) {
            float4 hv = *(const float4*)(hbase + r * HIDDEN + k4);
            acc[r].x += hv.x*w0.x + hv.y*w1.x + hv.z*w2.x + hv.w*w3.x;
            acc[r].y += hv.x*w0.y + hv.y*w1.y + hv.z*w2.y + hv.w*w3.y;
            acc[r].z += hv.x*w0.z + hv.y*w1.z + hv.z*w2.z + hv.w*w3.z;
            acc[r].w += hv.x*w0.w + hv.y*w1.w + hv.z*w2.w + hv.w*w3.w;
        }
    }

    #pragma unroll
    for (int r = 0; r < 8; r++) {
        int node = node0 + rg * 8 + r;
        if (node < N_NODES)
            ((float4*)(x + (size_t)node * HIDDEN))[c4] = acc[r];
    }
}

__global__ void batch_out_kernel(const int* __restrict__ bv, float* __restrict__ out) {
    int i = blockIdx.x * blockDim.x + threadIdx.x;
    if (i < N_NODES) out[i] = (float)bv[i];
}

// ---------------- CSR build ----------------

__global__ void zero_kernel(int* __restrict__ p, int n) {
    int i = blockIdx.x * blockDim.x + threadIdx.x;
    if (i < n) p[i] = 0;
}

__global__ void hist_kernel(const int* __restrict__ dst, int* __restrict__ cnt) {
    int e = blockIdx.x * blockDim.x + threadIdx.x;
    if (e < N_EDGES) atomicAdd(&cnt[dst[e]], 1);
}

__global__ void scan_partial_kernel(const int* __restrict__ cnt, int* __restrict__ bsum) {
    __shared__ int s[SCAN_BLOCK];
    int i = blockIdx.x * SCAN_BLOCK + threadIdx.x;
    s[threadIdx.x] = (i < N_NODES) ? cnt[i] : 0;
    __syncthreads();
    for (int off = SCAN_BLOCK / 2; off > 0; off >>= 1) {
        if (threadIdx.x < off) s[threadIdx.x] += s[threadIdx.x + off];
        __syncthreads();
    }
    if (threadIdx.x == 0) bsum[blockIdx.x] = s[0];
}

__global__ void scan_base_kernel(int* __restrict__ bsum) {
    __shared__ int s[512];
    int t = threadIdx.x;
    s[t] = (t < SCAN_GRID) ? bsum[t] : 0;
    __syncthreads();
    for (int off = 1; off < 512; off <<= 1) {
        int v = (t >= off) ? s[t - off] : 0;
        __syncthreads();
        s[t] += v;
        __syncthreads();
    }
    if (t < SCAN_GRID) bsum[t] = (t > 0) ? s[t - 1] : 0;
}

__global__ void scan_final_kernel(int* __restrict__ cnt, const int* __restrict__ bsum) {
    __shared__ int s[SCAN_BLOCK];
    int i = blockIdx.x * SCAN_BLOCK + threadIdx.x;
    int v = (i < N_NODES) ? cnt[i] : 0;
    s[threadIdx.x] = v;
    __syncthreads();
    for (int off = 1; off < SCAN_BLOCK; off <<= 1) {
        int u = (threadIdx.x >= off) ? s[threadIdx.x - off] : 0;
        __syncthreads();
        s[threadIdx.x] += u;
        __syncthreads();
    }
    if (i < N_NODES) cnt[i] = bsum[blockIdx.x] + s[threadIdx.x] - v;
}

// fp32 sea variant (fallback path)
__global__ void scatter2_kernel(const int* __restrict__ dst,
                                const int* __restrict__ src,
                                const float* __restrict__ edge_attr,
                                int* __restrict__ pos,
                                int* __restrict__ ssrc,
                                float4* __restrict__ sea) {
    int e = blockIdx.x * blockDim.x + threadIdx.x;
    if (e < N_EDGES) {
        int p = atomicAdd(&pos[dst[e]], 1);
        ssrc[p] = src[e];
        sea[p] = ((const float4*)edge_attr)[e];
    }
}

// fp16 sea variant (halfx path): 8 B/edge
__global__ void scatter3_kernel(const int* __restrict__ dst,
                                const int* __restrict__ src,
                                const float* __restrict__ edge_attr,
                                int* __restrict__ pos,
                                int* __restrict__ ssrc,
                                uint2* __restrict__ seah) {
    int e = blockIdx.x * blockDim.x + threadIdx.x;
    if (e < N_EDGES) {
        int p = atomicAdd(&pos[dst[e]], 1);
        ssrc[p] = src[e];
        seah[p] = f4toh8(((const float4*)edge_attr)[e]);
    }
}

// fp32 gather (round-0 proven loop shape) — fallback when no fp16 shadow
__global__ void gather2_kernel(const float* __restrict__ x,
                               const int* __restrict__ ssrc,
                               const float4* __restrict__ sea,
                               const int* __restrict__ pos,   // pos[i]=end; start=pos[i-1]
                               const float* __restrict__ We_l,
                               const float* __restrict__ be_l,
                               float* __restrict__ h) {
    __shared__ float sWe[EDGE_CH * HIDDEN];
    __shared__ float sbe[HIDDEN];
    for (int i = threadIdx.x; i < EDGE_CH * HIDDEN; i += blockDim.x) sWe[i] = We_l[i];
    if (threadIdx.x < HIDDEN) sbe[threadIdx.x] = be_l[threadIdx.x];
    __syncthreads();

    int t = blockIdx.x * blockDim.x + threadIdx.x;
    int node = t >> 5;
    int c4 = t & 31;
    if (node >= N_NODES) return;

    int start = (node == 0) ? 0 : pos[node - 1];
    int end = pos[node];

    float4 w0 = ((const float4*)sWe)[0 * 32 + c4];
    float4 w1 = ((const float4*)sWe)[1 * 32 + c4];
    float4 w2 = ((const float4*)sWe)[2 * 32 + c4];
    float4 w3 = ((const float4*)sWe)[3 * 32 + c4];
    float4 bb = ((const float4*)sbe)[c4];

    float4 acc = make_float4(0.f, 0.f, 0.f, 0.f);
    int j = start;
    if (j < end) {
        int s0 = ssrc[j];
        float4 ea0 = sea[j];
        for (; j + 1 < end; j++) {
            int s1 = ssrc[j + 1];
            float4 ea1 = sea[j + 1];
            float4 xv = ((const float4*)(x + (size_t)s0 * HIDDEN))[c4];
            float m0 = xv.x + ea0.x*w0.x + ea0.y*w1.x + ea0.z*w2.x + ea0.w*w3.x + bb.x;
            float m1 = xv.y + ea0.x*w0.y + ea0.y*w1.y + ea0.z*w2.y + ea0.w*w3.y + bb.y;
            float m2 = xv.z + ea0.x*w0.z + ea0.y*w1.z + ea0.z*w2.z + ea0.w*w3.z + bb.z;
            float m3 = xv.w + ea0.x*w0.w + ea0.y*w1.w + ea0.z*w2.w + ea0.w*w3.w + bb.w;
            acc.x += fmaxf(m0, 0.f); acc.y += fmaxf(m1, 0.f);
            acc.z += fmaxf(m2, 0.f); acc.w += fmaxf(m3, 0.f);
            s0 = s1; ea0 = ea1;
        }
        float4 xv = ((const float4*)(x + (size_t)s0 * HIDDEN))[c4];
        float m0 = xv.x + ea0.x*w0.x + ea0.y*w1.x + ea0.z*w2.x + ea0.w*w3.x + bb.x;
        float m1 = xv.y + ea0.x*w0.y + ea0.y*w1.y + ea0.z*w2.y + ea0.w*w3.y + bb.y;
        float m2 = xv.z + ea0.x*w0.z + ea0.y*w1.z + ea0.z*w2.z + ea0.w*w3.z + bb.z;
        float m3 = xv.w + ea0.x*w0.w + ea0.y*w1.w + ea0.z*w2.w + ea0.w*w3.w + bb.w;
        acc.x += fmaxf(m0, 0.f); acc.y += fmaxf(m1, 0.f);
        acc.z += fmaxf(m2, 0.f); acc.w += fmaxf(m3, 0.f);
    }
    float4 xi = ((const float4*)(x + (size_t)node * HIDDEN))[c4];
    acc.x += xi.x; acc.y += xi.y; acc.z += xi.z; acc.w += xi.w;
    ((float4*)(h + (size_t)node * HIDDEN))[c4] = acc;
}

// fp16-shadow gather v3: one full wave per node, edge list split across the
// two half-waves (even edges -> lanes 0-31, odd edges -> lanes 32-63). Each
// half runs the proven rotation loop with stride 2 -> 2x outstanding random
// reads per node (latency-chain halved). Partial fp32 sums combined with 4
// intra-wave shuffles; half 0 adds the self term and stores.
__global__ void gather4_kernel(const __half* __restrict__ xh,
                               const int* __restrict__ ssrc,
                               const uint2* __restrict__ seah,
                               const int* __restrict__ pos,   // pos[i]=end; start=pos[i-1]
                               const float* __restrict__ We_l,
                               const float* __restrict__ be_l,
                               __half* __restrict__ h) {
    __shared__ float sWe[EDGE_CH * HIDDEN];
    __shared__ float sbe[HIDDEN];
    for (int i = threadIdx.x; i < EDGE_CH * HIDDEN; i += blockDim.x) sWe[i] = We_l[i];
    if (threadIdx.x < HIDDEN) sbe[threadIdx.x] = be_l[threadIdx.x];
    __syncthreads();

    int t = blockIdx.x * blockDim.x + threadIdx.x;
    int node = t >> 6;                 // one full wave per node
    int par  = (t >> 5) & 1;           // half-wave id: 0 = even edges, 1 = odd
    int c4   = t & 31;
    if (node >= N_NODES) return;

    int start = (node == 0) ? 0 : pos[node - 1];
    int end = pos[node];

    float4 w0 = ((const float4*)sWe)[0 * 32 + c4];
    float4 w1 = ((const float4*)sWe)[1 * 32 + c4];
    float4 w2 = ((const float4*)sWe)[2 * 32 + c4];
    float4 w3 = ((const float4*)sWe)[3 * 32 + c4];
    float4 bb = ((const float4*)sbe)[c4];

    // per-lane fp16 weight/bias registers (converted once)
    __half2 w0l = __floats2half2_rn(w0.x, w0.y), w0h = __floats2half2_rn(w0.z, w0.w);
    __half2 w1l = __floats2half2_rn(w1.x, w1.y), w1h = __floats2half2_rn(w1.z, w1.w);
    __half2 w2l = __floats2half2_rn(w2.x, w2.y), w2h = __floats2half2_rn(w2.z, w2.w);
    __half2 w3l = __floats2half2_rn(w3.x, w3.y), w3h = __floats2half2_rn(w3.z, w3.w);
    __half2 bbl = __floats2half2_rn(bb.x, bb.y), bbh = __floats2half2_rn(bb.z, bb.w);

    float4 acc = make_float4(0.f, 0.f, 0.f, 0.f);

#define GACCH(xu, eu) do {                                                      \
        __half2 xl  = *reinterpret_cast<const __half2*>(&(xu).x);               \
        __half2 xh2 = *reinterpret_cast<const __half2*>(&(xu).y);               \
        __half2 ea01 = *reinterpret_cast<const __half2*>(&(eu).x);              \
        __half2 ea23 = *reinterpret_cast<const __half2*>(&(eu).y);              \
        __half2 e0 = __half2half2(__low2half(ea01));                            \
        __half2 e1 = __half2half2(__high2half(ea01));                           \
        __half2 e2 = __half2half2(__low2half(ea23));                            \
        __half2 e3 = __half2half2(__high2half(ea23));                           \
        __half2 ml = __hadd2(xl, bbl);                                          \
        __half2 mh = __hadd2(xh2, bbh);                                         \
        ml = __hfma2(e0, w0l, ml); mh = __hfma2(e0, w0h, mh);                   \
        ml = __hfma2(e1, w1l, ml); mh = __hfma2(e1, w1h, mh);                   \
        ml = __hfma2(e2, w2l, ml); mh = __hfma2(e2, w2h, mh);                   \
        ml = __hfma2(e3, w3l, ml); mh = __hfma2(e3, w3h, mh);                   \
        ml = pkmax0(ml); mh = pkmax0(mh);                                       \
        float2 f0 = __half22float2(ml), f1 = __half22float2(mh);                \
        acc.x += f0.x; acc.y += f0.y; acc.z += f1.x; acc.w += f1.y;             \
    } while (0)

    int j = start + par;
    if (j < end) {
        int s0 = ssrc[j];
        uint2 ea0 = seah[j];
        for (; j + 2 < end; j += 2) {
            int s1 = ssrc[j + 2];
            uint2 ea1 = seah[j + 2];
            uint2 xu = ((const uint2*)(xh + (size_t)s0 * HIDDEN))[c4];
            GACCH(xu, ea0);
            s0 = s1; ea0 = ea1;
        }
        uint2 xu = ((const uint2*)(xh + (size_t)s0 * HIDDEN))[c4];
        GACCH(xu, ea0);
    }
#undef GACCH

    // combine the two half-wave partial sums (lanes L and L+32 share channels)
    acc.x += __shfl_xor(acc.x, 32, 64);
    acc.y += __shfl_xor(acc.y, 32, 64);
    acc.z += __shfl_xor(acc.z, 32, 64);
    acc.w += __shfl_xor(acc.w, 32, 64);

    if (par == 0) {
        float4 xi = h8tof4(((const uint2*)(xh + (size_t)node * HIDDEN))[c4]);
        acc.x += xi.x; acc.y += xi.y; acc.z += xi.z; acc.w += xi.w;
        ((uint2*)(h + (size_t)node * HIDDEN))[c4] = f4toh8(acc);
    }
}

// ---------------- Level C fallback: atomics ----------------

__global__ void edge_kernel(const float* __restrict__ x,
                            const float* __restrict__ edge_attr,
                            const int* __restrict__ src,
                            const int* __restrict__ dst,
                            const float* __restrict__ We_l,
                            const float* __restrict__ be_l,
                            float* __restrict__ agg) {
    __shared__ float sWe[EDGE_CH * HIDDEN];
    __shared__ float sbe[HIDDEN];
    for (int i = threadIdx.x; i < EDGE_CH * HIDDEN; i += blockDim.x) sWe[i] = We_l[i];
    if (threadIdx.x < HIDDEN) sbe[threadIdx.x] = be_l[threadIdx.x];
    __syncthreads();

    int t = blockIdx.x * blockDim.x + threadIdx.x;
    int e = t >> 5;
    if (e >= N_EDGES) return;
    int c4 = t & 31;

    int s = src[e];
    int d = dst[e];
    float4 ea = ((const float4*)edge_attr)[e];
    float4 w0 = ((const float4*)sWe)[0 * 32 + c4];
    float4 w1 = ((const float4*)sWe)[1 * 32 + c4];
    float4 w2 = ((const float4*)sWe)[2 * 32 + c4];
    float4 w3 = ((const float4*)sWe)[3 * 32 + c4];
    float4 bb = ((const float4*)sbe)[c4];
    float4 xv = ((const float4*)(x + (size_t)s * HIDDEN))[c4];

    float m0 = xv.x + ea.x*w0.x + ea.y*w1.x + ea.z*w2.x + ea.w*w3.x + bb.x;
    float m1 = xv.y + ea.x*w0.y + ea.y*w1.y + ea.z*w2.y + ea.w*w3.y + bb.y;
    float m2 = xv.z + ea.x*w0.z + ea.y*w1.z + ea.z*w2.z + ea.w*w3.z + bb.z;
    float m3 = xv.w + ea.x*w0.w + ea.y*w1.w + ea.z*w2.w + ea.w*w3.w + bb.w;

    float* ap = agg + (size_t)d * HIDDEN + c4 * 4;
    atomicAdd(ap + 0, fmaxf(m0, 0.f));
    atomicAdd(ap + 1, fmaxf(m1, 0.f));
    atomicAdd(ap + 2, fmaxf(m2, 0.f));
    atomicAdd(ap + 3, fmaxf(m3, 0.f));
}

// ---------------- host ----------------

extern "C" void kernel_launch(void* const* d_in, const int* in_sizes, int n_in,
                              void* d_out, int out_size, void* d_ws, size_t ws_size,
                              hipStream_t stream) {
    const float* emb       = (const float*)d_in[0];
    const float* We        = (const float*)d_in[1];
    const float* be        = (const float*)d_in[2];
    const float* W1        = (const float*)d_in[3];
    const float* b1        = (const float*)d_in[4];
    const float* W2        = (const float*)d_in[5];
    const float* b2        = (const float*)d_in[6];
    const float* edge_attr = (const float*)d_in[7];
    const int*   z         = (const int*)d_in[8];
    const int*   ei        = (const int*)d_in[9];
    const int*   bv        = (const int*)d_in[10];

    float* x   = (float*)d_out;
    float* agg = (float*)d_ws;
    const int* src = ei;
    const int* dst = ei + N_EDGES;

    const size_t AGG_BYTES  = (size_t)N_NODES * HIDDEN * sizeof(float);     // 51.2 MB
    const size_t POS_BYTES  = (size_t)N_NODES * sizeof(int);                // 0.4 MB
    const size_t SRC_BYTES  = (size_t)N_EDGES * sizeof(int);                // 2.4 MB
    const size_t EA_BYTES   = (size_t)N_EDGES * 4 * sizeof(float);          // 9.6 MB
    const size_t BSUM_BYTES = ((size_t)SCAN_GRID * sizeof(int) + 15) & ~15; // 1568 B
    const size_t WT_ELEMS   = (size_t)NUM_LAYERS * 2 * HIDDEN * HIDDEN;     // 98304
    const size_t WT_BYTES   = WT_ELEMS * sizeof(unsigned short);            // 196608 B
    const size_t XH_BYTES   = (size_t)N_NODES * HIDDEN * sizeof(__half);    // 25.6 MB

    const size_t OFF_POS  = AGG_BYTES;
    const size_t OFF_SRC  = OFF_POS + POS_BYTES;
    const size_t OFF_EA   = OFF_SRC + SRC_BYTES;
    const size_t OFF_BSUM = OFF_EA + EA_BYTES;
    const size_t OFF_WT   = OFF_BSUM + BSUM_BYTES;
    const size_t OFF_XH   = OFF_WT + WT_BYTES;
    const size_t TOTAL    = OFF_WT + WT_BYTES;
    const size_t TOTAL2   = OFF_XH + XH_BYTES;

    const int MLP_GRID = (N_NODES + MLP_ROWS - 1) / MLP_ROWS;

    if (ws_size >= OFF_BSUM + BSUM_BYTES) {
        // Level A: de-indirected CSR + parallel scan
        int*    pos  = (int*)((char*)d_ws + OFF_POS);
        int*    ssrc = (int*)((char*)d_ws + OFF_SRC);
        float4* sea  = (float4*)((char*)d_ws + OFF_EA);
        uint2*  seah = (uint2*)((char*)d_ws + OFF_EA);
        int*    bsum = (int*)((char*)d_ws + OFF_BSUM);
        const bool mfma  = (ws_size >= TOTAL);
        const bool halfx = (ws_size >= TOTAL2);
        unsigned short* wt = (unsigned short*)((char*)d_ws + OFF_WT);
        __half* xh = (__half*)((char*)d_ws + OFF_XH);

        // fused setup: embed (x or xh) + pos zero + batch_out + wprep
        setup_kernel<<<EMB_BLOCKS + ZB_BLOCKS + WP_BLOCKS, 256, 0, stream>>>(
            emb, z, x, xh, halfx ? 1 : 0, halfx ? 0 : 1,
            pos, bv, x + (size_t)N_NODES * HIDDEN,
            W1, W2, wt, mfma ? 1 : 0);
        hist_kernel<<<(N_EDGES + 255) / 256, 256, 0, stream>>>(dst, pos);
        scan_partial_kernel<<<SCAN_GRID, SCAN_BLOCK, 0, stream>>>(pos, bsum);
        scan_base_kernel<<<1, 512, 0, stream>>>(bsum);
        scan_final_kernel<<<SCAN_GRID, SCAN_BLOCK, 0, stream>>>(pos, bsum);
        if (halfx)
            scatter3_kernel<<<(N_EDGES + 255) / 256, 256, 0, stream>>>(dst, src, edge_attr, pos, ssrc, seah);
        else
            scatter2_kernel<<<(N_EDGES + 255) / 256, 256, 0, stream>>>(dst, src, edge_attr, pos, ssrc, sea);

        for (int l = 0; l < NUM_LAYERS; l++) {
            if (halfx) {
                gather4_kernel<<<(N_NODES * 64 + 255) / 256, 256, 0, stream>>>(
                    xh, ssrc, seah, pos,
                    We + (size_t)l * EDGE_CH * HIDDEN, be + (size_t)l * HIDDEN,
                    (__half*)agg);
            } else {
                gather2_kernel<<<(N_NODES * 32 + 255) / 256, 256, 0, stream>>>(
                    x, ssrc, sea, pos,
                    We + (size_t)l * EDGE_CH * HIDDEN, be + (size_t)l * HIDDEN, agg);
            }
            if (mfma) {
                int wx  = (!halfx || l == NUM_LAYERS - 1) ? 1 : 0;
                int wxh = (halfx && l < NUM_LAYERS - 1) ? 1 : 0;
                mlp_mfma5_kernel<<<MLP5_GRID, 1024, 0, stream>>>(
                    (const void*)agg, halfx ? 1 : 0,
                    wt + (size_t)(l * 2) * HIDDEN * HIDDEN,
                    b1 + (size_t)l * HIDDEN, b2 + (size_t)l * HIDDEN, x, xh, wx, wxh);
            } else {
                mlp_kernel<<<MLP_GRID, 256, 0, stream>>>(
                    agg,
                    W1 + (size_t)l * HIDDEN * HIDDEN, b1 + (size_t)l * HIDDEN,
                    W2 + (size_t)l * HIDDEN * HIDDEN, b2 + (size_t)l * HIDDEN, x);
            }
        }
    } else {
        // Level C: atomic fallback
        embed_init_kernel<<<(N_NODES * 32) / 256, 256, 0, stream>>>(
            emb, z, x, agg, 1, (__half*)nullptr, 0, 1);
        for (int l = 0; l < NUM_LAYERS; l++) {
            edge_kernel<<<(N_EDGES * 32) / 256, 256, 0, stream>>>(
                x, edge_attr, src, dst,
                We + (size_t)l * EDGE_CH * HIDDEN, be + (size_t)l * HIDDEN, agg);
            mlp_kernel<<<MLP_GRID, 256, 0, stream>>>(
                agg,
                W1 + (size_t)l * HIDDEN * HIDDEN, b1 + (size_t)l * HIDDEN,
                W2 + (size_t)l * HIDDEN * HIDDEN, b2 + (size_t)l * HIDDEN, x);
        }
        batch_out_kernel<<<(N_NODES + 255) / 256, 256, 0, stream>>>(bv, x + (size_t)N_NODES * HIDDEN);
    }
}

// Round 10
// 405.832 us; speedup vs baseline: 1.0755x; 1.0755x over previous
//
#include <hip/hip_runtime.h>
#include <hip/hip_fp16.h>
#include <math.h>

#define N_NODES 100000
#define N_EDGES 600000
#define HIDDEN 128
#define EDGE_CH 4
#define NUM_LAYERS 3
#define MLP_ROWS 64   // nodes per block in fp32 fallback mlp_kernel

#define SCAN_BLOCK 256
#define SCAN_GRID ((N_NODES + SCAN_BLOCK - 1) / SCAN_BLOCK)   // 391

#define TSTR 68             // padded LDS row stride (floats), half-width transpose
#define MLP5_TILES ((N_NODES + 255) / 256)   // 391 (256 nodes per 16-wave block)
#define MLP5_GRID 256       // 1 block/CU (LDS-bound), grid-stride over tiles

// setup_kernel block ranges
#define EMB_BLOCKS ((N_NODES * 32) / 256)    // 12500
#define ZB_BLOCKS  ((N_NODES + 255) / 256)   // 391
#define WP_BLOCKS  ((NUM_LAYERS * 2 * HIDDEN * HIDDEN) / 256)  // 384

typedef short bf16x8 __attribute__((ext_vector_type(8)));
typedef float f32x4  __attribute__((ext_vector_type(4)));

__device__ inline unsigned short f2bf(float x) {           // RNE fp32 -> bf16 bits
    unsigned u = __float_as_uint(x);
    return (unsigned short)((u + 0x7fff + ((u >> 16) & 1)) >> 16);
}
__device__ inline float bf2f(unsigned short b) { return __uint_as_float(((unsigned)b) << 16); }

__device__ inline float4 h8tof4(uint2 u) {                 // 4 packed halves -> float4
    __half2 a = *reinterpret_cast<const __half2*>(&u.x);
    __half2 b = *reinterpret_cast<const __half2*>(&u.y);
    float2 fa = __half22float2(a);
    float2 fb = __half22float2(b);
    return make_float4(fa.x, fa.y, fb.x, fb.y);
}
__device__ inline uint2 f4toh8(float4 v) {                 // float4 -> 4 packed halves
    __half2 a = __floats2half2_rn(v.x, v.y);
    __half2 b = __floats2half2_rn(v.z, v.w);
    uint2 u;
    u.x = *reinterpret_cast<unsigned*>(&a);
    u.y = *reinterpret_cast<unsigned*>(&b);
    return u;
}

// packed relu: max(x, 0) on 2 halves via v_pk_max_f16 (no __hmax2 in ROCm 7.2)
__device__ inline __half2 pkmax0(__half2 a) {
    unsigned ua = *reinterpret_cast<unsigned*>(&a);
    unsigned r;
    asm("v_pk_max_f16 %0, %1, %2" : "=v"(r) : "v"(ua), "v"(0u));
    return *reinterpret_cast<__half2*>(&r);
}

// ---------------- fused setup: embed + zero(pos) + batch_out + wprep ----------------

__global__ void setup_kernel(const float* __restrict__ emb,
                             const int* __restrict__ z,
                             float* __restrict__ x,
                             __half* __restrict__ xh,
                             int write_xh, int write_x,
                             int* __restrict__ pos,
                             const int* __restrict__ bv,
                             float* __restrict__ out,
                             const float* __restrict__ W1,
                             const float* __restrict__ W2,
                             unsigned short* __restrict__ wt,
                             int do_wprep) {
    int b = blockIdx.x;
    if (b < EMB_BLOCKS) {
        int t = b * 256 + threadIdx.x;
        int node = t >> 5;
        int c4 = t & 31;
        if (node < N_NODES) {
            float4 v = ((const float4*)(emb + (size_t)z[node] * HIDDEN))[c4];
            if (write_x)
                ((float4*)(x + (size_t)node * HIDDEN))[c4] = v;
            if (write_xh)
                ((uint2*)(xh + (size_t)node * HIDDEN))[c4] = f4toh8(v);
        }
    } else if (b < EMB_BLOCKS + ZB_BLOCKS) {
        int i = (b - EMB_BLOCKS) * 256 + threadIdx.x;
        if (i < N_NODES) {
            pos[i] = 0;
            out[i] = (float)bv[i];
        }
    } else if (do_wprep) {
        int idx = (b - EMB_BLOCKS - ZB_BLOCKS) * 256 + threadIdx.x;
        if (idx < NUM_LAYERS * 2 * HIDDEN * HIDDEN) {
            int j    = idx & 7;
            int lane = (idx >> 3) & 63;
            int ks   = (idx >> 9) & 3;
            int nt   = (idx >> 11) & 7;
            int mat  = (idx >> 14) & 1;
            int l    = idx >> 15;
            int n = nt * 16 + (lane & 15);
            int k = ks * 32 + (lane >> 4) * 8 + j;
            const float* W = mat ? W2 : W1;
            wt[idx] = f2bf(W[(size_t)l * HIDDEN * HIDDEN + (size_t)k * HIDDEN + n]);
        }
    }
}

// ---------------- common kernels (fallback paths) ----------------

__global__ void embed_init_kernel(const float* __restrict__ emb,
                                  const int* __restrict__ z,
                                  float* __restrict__ x,
                                  float* __restrict__ agg,
                                  int write_agg,
                                  __half* __restrict__ xh,
                                  int write_xh,
                                  int write_x) {
    int t = blockIdx.x * blockDim.x + threadIdx.x;
    int node = t >> 5;
    int c4 = t & 31;
    if (node < N_NODES) {
        float4 v = ((const float4*)(emb + (size_t)z[node] * HIDDEN))[c4];
        if (write_x)
            ((float4*)(x + (size_t)node * HIDDEN))[c4] = v;
        if (write_agg)
            ((float4*)(agg + (size_t)node * HIDDEN))[c4] = v;
        if (write_xh)
            ((uint2*)(xh + (size_t)node * HIDDEN))[c4] = f4toh8(v);
    }
}

// MFMA MLP v5: 1024 threads / 16 waves per block -> 4 waves/SIMD.
// Both weight images in LDS (64 KB); half-width (TSTR=68) wave-private
// transpose buffers (69.6 KB) -> 133.6 KB total, 1 block/CU. GEMM2 is
// ks-interleaved through the half-width buffer. No block barriers in the
// main loop. A = exact input as bf16 hi+lo (2 MFMAs per fragment).
__global__ __launch_bounds__(1024, 1) void mlp_mfma5_kernel(
        const void* __restrict__ hbuf,
        int h_half,
        const unsigned short* __restrict__ wfrag,  // this layer's [2][8][4][64][8] image
        const float* __restrict__ b1, const float* __restrict__ b2,
        float* __restrict__ x,
        __half* __restrict__ xh,
        int write_x, int write_xh) {
    __shared__ short wlds[2 * 16384];              // 64 KB: both matrices, fragment order
    __shared__ float tbuf[16 * 16 * TSTR];         // 69.6 KB: per-wave half-width buffers
    int tid   = threadIdx.x;
    int wave  = tid >> 6;
    int lane  = tid & 63;
    int row16 = lane & 15;
    int quad  = lane >> 4;
    float* myt = tbuf + wave * 16 * TSTR;

    // stage both weight images linearly (4096 float4)
    for (int i = tid; i < 4096; i += 1024)
        ((float4*)wlds)[i] = ((const float4*)wfrag)[i];
    __syncthreads();                               // only barrier in the kernel

    // per-lane biases (column = nt*16+row16), hoisted out of the tile loop
    float bias1[8], bias2[8];
    #pragma unroll
    for (int nt = 0; nt < 8; nt++) {
        bias1[nt] = b1[nt * 16 + row16];
        bias2[nt] = b2[nt * 16 + row16];
    }

    for (int tile = blockIdx.x; tile < MLP5_TILES; tile += gridDim.x) {
        int wnode0 = tile * 256 + wave * 16;
        int mnode  = wnode0 + row16;
        bool valid = (mnode < N_NODES);
        int srcnode = valid ? mnode : 0;

        // ---- A1 fragments straight from global h (fp16 or fp32) ----
        bf16x8 ahi[4], alo[4];
        if (h_half) {
            const __half* hrow = (const __half*)hbuf + (size_t)srcnode * HIDDEN + quad * 8;
            #pragma unroll
            for (int ks = 0; ks < 4; ks++) {
                float v[8];
                if (valid) {
                    uint4 u = *(const uint4*)(hrow + ks * 32);   // 8 halves, 16 B
                    const __half2* hp = reinterpret_cast<const __half2*>(&u);
                    float2 f0 = __half22float2(hp[0]);
                    float2 f1 = __half22float2(hp[1]);
                    float2 f2 = __half22float2(hp[2]);
                    float2 f3 = __half22float2(hp[3]);
                    v[0]=f0.x; v[1]=f0.y; v[2]=f1.x; v[3]=f1.y;
                    v[4]=f2.x; v[5]=f2.y; v[6]=f3.x; v[7]=f3.y;
                } else {
                    #pragma unroll
                    for (int j = 0; j < 8; j++) v[j] = 0.f;
                }
                bf16x8 hi, lo;
                #pragma unroll
                for (int j = 0; j < 8; j++) {
                    unsigned short hb = f2bf(v[j]);
                    hi[j] = (short)hb;
                    lo[j] = (short)f2bf(v[j] - bf2f(hb));
                }
                ahi[ks] = hi; alo[ks] = lo;
            }
        } else {
            const float* hrow = (const float*)hbuf + (size_t)srcnode * HIDDEN + quad * 8;
            #pragma unroll
            for (int ks = 0; ks < 4; ks++) {
                float v[8];
                *(float4*)(v + 0) = valid ? *(const float4*)(hrow + ks * 32 + 0) : make_float4(0.f,0.f,0.f,0.f);
                *(float4*)(v + 4) = valid ? *(const float4*)(hrow + ks * 32 + 4) : make_float4(0.f,0.f,0.f,0.f);
                bf16x8 hi, lo;
                #pragma unroll
                for (int j = 0; j < 8; j++) {
                    unsigned short hb = f2bf(v[j]);
                    hi[j] = (short)hb;
                    lo[j] = (short)f2bf(v[j] - bf2f(hb));
                }
                ahi[ks] = hi; alo[ks] = lo;
            }
        }

        // ---- GEMM1: B (W1) from LDS, 8 independent acc chains ----
        f32x4 acc1[8];
        #pragma unroll
        for (int nt = 0; nt < 8; nt++) acc1[nt] = (f32x4){0.f, 0.f, 0.f, 0.f};
        #pragma unroll
        for (int ks = 0; ks < 4; ks++) {
            #pragma unroll
            for (int nt = 0; nt < 8; nt++) {
                bf16x8 Bv = *(const bf16x8*)(wlds + (size_t)((nt * 4 + ks) * 64 + lane) * 8);
                acc1[nt] = __builtin_amdgcn_mfma_f32_16x16x32_bf16(ahi[ks], Bv, acc1[nt], 0, 0, 0);
                acc1[nt] = __builtin_amdgcn_mfma_f32_16x16x32_bf16(alo[ks], Bv, acc1[nt], 0, 0, 0);
            }
        }

        // ---- GEMM2, ks-interleaved through half-width wave-private buffer ----
        f32x4 acc2[8];
        #pragma unroll
        for (int nt = 0; nt < 8; nt++) acc2[nt] = (f32x4){0.f, 0.f, 0.f, 0.f};

        #pragma unroll
        for (int p = 0; p < 2; p++) {
            // bias + silu for 4 col-tiles -> wave-private LDS (cols 64p..64p+63)
            #pragma unroll
            for (int l4 = 0; l4 < 4; l4++) {
                int nt = p * 4 + l4;
                #pragma unroll
                for (int r = 0; r < 4; r++) {
                    float v = acc1[nt][r] + bias1[nt];
                    v = v / (1.f + __expf(-v));
                    myt[(quad * 4 + r) * TSTR + l4 * 16 + row16] = v;
                }
            }
            // wave-synchronous: same wave reads below; lgkmcnt ordering suffices

            // A2 fragments for ks = 2p, 2p+1
            bf16x8 a2hi[2], a2lo[2];
            #pragma unroll
            for (int kk = 0; kk < 2; kk++) {
                const float* pp = myt + row16 * TSTR + kk * 32 + quad * 8;
                float v[8];
                *(float4*)(v + 0) = *(const float4*)(pp + 0);
                *(float4*)(v + 4) = *(const float4*)(pp + 4);
                bf16x8 hi, lo;
                #pragma unroll
                for (int j = 0; j < 8; j++) {
                    unsigned short hb = f2bf(v[j]);
                    hi[j] = (short)hb;
                    lo[j] = (short)f2bf(v[j] - bf2f(hb));
                }
                a2hi[kk] = hi; a2lo[kk] = lo;
            }

            // partial GEMM2 with B (W2) from LDS
            #pragma unroll
            for (int kk = 0; kk < 2; kk++) {
                int ks = p * 2 + kk;
                #pragma unroll
                for (int nt = 0; nt < 8; nt++) {
                    bf16x8 Bv = *(const bf16x8*)(wlds + (size_t)(16384 + ((nt * 4 + ks) * 64 + lane) * 8));
                    acc2[nt] = __builtin_amdgcn_mfma_f32_16x16x32_bf16(a2hi[kk], Bv, acc2[nt], 0, 0, 0);
                    acc2[nt] = __builtin_amdgcn_mfma_f32_16x16x32_bf16(a2lo[kk], Bv, acc2[nt], 0, 0, 0);
                }
            }
        }

        // ---- epilogue: transpose through LDS, coalesced >=64B/lane stores ----
        int onode = wnode0 + row16;
        if (write_xh) {
            // full-width fp16 transpose reusing the f32 buffer (stride 136 halves)
            __half* hmyt = (__half*)myt;
            #pragma unroll
            for (int nt = 0; nt < 8; nt++) {
                #pragma unroll
                for (int r = 0; r < 4; r++)
                    hmyt[(quad * 4 + r) * 136 + nt * 16 + row16] =
                        __float2half_rn(acc2[nt][r] + bias2[nt]);
            }
            if (onode < N_NODES) {
                const uint4* pr = (const uint4*)(hmyt + row16 * 136 + quad * 32);
                uint4* orow = (uint4*)(xh + (size_t)onode * HIDDEN + quad * 32);
                #pragma unroll
                for (int j = 0; j < 4; j++) orow[j] = pr[j];
            }
        }
        if (write_x) {
            // two half-width fp32 passes
            #pragma unroll
            for (int p = 0; p < 2; p++) {
                #pragma unroll
                for (int l4 = 0; l4 < 4; l4++) {
                    int nt = p * 4 + l4;
                    #pragma unroll
                    for (int r = 0; r < 4; r++)
                        myt[(quad * 4 + r) * TSTR + l4 * 16 + row16] = acc2[nt][r] + bias2[nt];
                }
                if (onode < N_NODES) {
                    const float* prow = myt + row16 * TSTR + quad * 16;
                    float* orow = x + (size_t)onode * HIDDEN + p * 64 + quad * 16;
                    #pragma unroll
                    for (int j = 0; j < 4; j++)
                        *(float4*)(orow + 4 * j) = *(const float4*)(prow + 4 * j);
                }
            }
        }
    }
}

// fp32 fallback MLP
__global__ void mlp_kernel(const float* __restrict__ h,
                           const float* __restrict__ W1, const float* __restrict__ b1,
                           const float* __restrict__ W2, const float* __restrict__ b2,
                           float* __restrict__ x) {
    __shared__ float hs[MLP_ROWS * HIDDEN];
    int rg = threadIdx.x >> 5;
    int c4 = threadIdx.x & 31;
    int node0 = blockIdx.x * MLP_ROWS;

    for (int i = threadIdx.x; i < MLP_ROWS * 32; i += 256) {
        int node = node0 + (i >> 5);
        float4 v = (node < N_NODES)
                 ? ((const float4*)(h + (size_t)node * HIDDEN))[i & 31]
                 : make_float4(0.f, 0.f, 0.f, 0.f);
        ((float4*)hs)[i] = v;
    }
    __syncthreads();

    float4 acc[8];
    {
        float4 bv = ((const float4*)b1)[c4];
        #pragma unroll
        for (int r = 0; r < 8; r++) acc[r] = bv;
    }
    const float* hbase = hs + rg * 8 * HIDDEN;

    for (int k4 = 0; k4 < HIDDEN; k4 += 4) {
        float4 w0 = ((const float4*)(W1 + (size_t)(k4 + 0) * HIDDEN))[c4];
        float4 w1 = ((const float4*)(W1 + (size_t)(k4 + 1) * HIDDEN))[c4];
        float4 w2 = ((const float4*)(W1 + (size_t)(k4 + 2) * HIDDEN))[c4];
        float4 w3 = ((const float4*)(W1 + (size_t)(k4 + 3) * HIDDEN))[c4];
        #pragma unroll
        for (int r = 0; r < 8; r++) {
            float4 hv = *(const float4*)(hbase + r * HIDDEN + k4);
            acc[r].x += hv.x*w0.x + hv.y*w1.x + hv.z*w2.x + hv.w*w3.x;
            acc[r].y += hv.x*w0.y + hv.y*w1.y + hv.z*w2.y + hv.w*w3.y;
            acc[r].z += hv.x*w0.z + hv.y*w1.z + hv.z*w2.z + hv.w*w3.z;
            acc[r].w += hv.x*w0.w + hv.y*w1.w + hv.z*w2.w + hv.w*w3.w;
        }
    }

    __syncthreads();
    #pragma unroll
    for (int r = 0; r < 8; r++) {
        float4 a = acc[r];
        a.x = a.x / (1.f + __expf(-a.x));
        a.y = a.y / (1.f + __expf(-a.y));
        a.z = a.z / (1.f + __expf(-a.z));
        a.w = a.w / (1.f + __expf(-a.w));
        *(float4*)(hs + (rg * 8 + r) * HIDDEN + c4 * 4) = a;
    }
    __syncthreads();

    {
        float4 bv = ((const float4*)b2)[c4];
        #pragma unroll
        for (int r = 0; r < 8; r++) acc[r] = bv;
    }
    for (int k4 = 0; k4 < HIDDEN; k4 += 4) {
        float4 w0 = ((const float4*)(W2 + (size_t)(k4 + 0) * HIDDEN))[c4];
        float4 w1 = ((const float4*)(W2 + (size_t)(k4 + 1) * HIDDEN))[c4];
        float4 w2 = ((const float4*)(W2 + (size_t)(k4 + 2) * HIDDEN))[c4];
        float4 w3 = ((const float4*)(W2 + (size_t)(k4 + 3) * HIDDEN))[c4];
        #pragma unroll
        for (int r = 0; r < 8; r++) {
            float4 hv = *(const float4*)(hbase + r * HIDDEN + k4);
            acc[r].x += hv.x*w0.x + hv.y*w1.x + hv.z*w2.x + hv.w*w3.x;
            acc[r].y += hv.x*w0.y + hv.y*w1.y + hv.z*w2.y + hv.w*w3.y;
            acc[r].z += hv.x*w0.z + hv.y*w1.z + hv.z*w2.z + hv.w*w3.z;
            acc[r].w += hv.x*w0.w + hv.y*w1.w + hv.z*w2.w + hv.w*w3.w;
        }
    }

    #pragma unroll
    for (int r = 0; r < 8; r++) {
        int node = node0 + rg * 8 + r;
        if (node < N_NODES)
            ((float4*)(x + (size_t)node * HIDDEN))[c4] = acc[r];
    }
}

__global__ void batch_out_kernel(const int* __restrict__ bv, float* __restrict__ out) {
    int i = blockIdx.x * blockDim.x + threadIdx.x;
    if (i < N_NODES) out[i] = (float)bv[i];
}

// ---------------- CSR build ----------------

__global__ void zero_kernel(int* __restrict__ p, int n) {
    int i = blockIdx.x * blockDim.x + threadIdx.x;
    if (i < n) p[i] = 0;
}

__global__ void hist_kernel(const int* __restrict__ dst, int* __restrict__ cnt) {
    int e = blockIdx.x * blockDim.x + threadIdx.x;
    if (e < N_EDGES) atomicAdd(&cnt[dst[e]], 1);
}

__global__ void scan_partial_kernel(const int* __restrict__ cnt, int* __restrict__ bsum) {
    __shared__ int s[SCAN_BLOCK];
    int i = blockIdx.x * SCAN_BLOCK + threadIdx.x;
    s[threadIdx.x] = (i < N_NODES) ? cnt[i] : 0;
    __syncthreads();
    for (int off = SCAN_BLOCK / 2; off > 0; off >>= 1) {
        if (threadIdx.x < off) s[threadIdx.x] += s[threadIdx.x + off];
        __syncthreads();
    }
    if (threadIdx.x == 0) bsum[blockIdx.x] = s[0];
}

__global__ void scan_base_kernel(int* __restrict__ bsum) {
    __shared__ int s[512];
    int t = threadIdx.x;
    s[t] = (t < SCAN_GRID) ? bsum[t] : 0;
    __syncthreads();
    for (int off = 1; off < 512; off <<= 1) {
        int v = (t >= off) ? s[t - off] : 0;
        __syncthreads();
        s[t] += v;
        __syncthreads();
    }
    if (t < SCAN_GRID) bsum[t] = (t > 0) ? s[t - 1] : 0;
}

__global__ void scan_final_kernel(int* __restrict__ cnt, const int* __restrict__ bsum) {
    __shared__ int s[SCAN_BLOCK];
    int i = blockIdx.x * SCAN_BLOCK + threadIdx.x;
    int v = (i < N_NODES) ? cnt[i] : 0;
    s[threadIdx.x] = v;
    __syncthreads();
    for (int off = 1; off < SCAN_BLOCK; off <<= 1) {
        int u = (threadIdx.x >= off) ? s[threadIdx.x - off] : 0;
        __syncthreads();
        s[threadIdx.x] += u;
        __syncthreads();
    }
    if (i < N_NODES) cnt[i] = bsum[blockIdx.x] + s[threadIdx.x] - v;
}

// fp32 sea variant (fallback path)
__global__ void scatter2_kernel(const int* __restrict__ dst,
                                const int* __restrict__ src,
                                const float* __restrict__ edge_attr,
                                int* __restrict__ pos,
                                int* __restrict__ ssrc,
                                float4* __restrict__ sea) {
    int e = blockIdx.x * blockDim.x + threadIdx.x;
    if (e < N_EDGES) {
        int p = atomicAdd(&pos[dst[e]], 1);
        ssrc[p] = src[e];
        sea[p] = ((const float4*)edge_attr)[e];
    }
}

// fp16 sea variant (halfx path): 8 B/edge
__global__ void scatter3_kernel(const int* __restrict__ dst,
                                const int* __restrict__ src,
                                const float* __restrict__ edge_attr,
                                int* __restrict__ pos,
                                int* __restrict__ ssrc,
                                uint2* __restrict__ seah) {
    int e = blockIdx.x * blockDim.x + threadIdx.x;
    if (e < N_EDGES) {
        int p = atomicAdd(&pos[dst[e]], 1);
        ssrc[p] = src[e];
        seah[p] = f4toh8(((const float4*)edge_attr)[e]);
    }
}

// fp32 gather (round-0 proven loop shape) — fallback when no fp16 shadow
__global__ void gather2_kernel(const float* __restrict__ x,
                               const int* __restrict__ ssrc,
                               const float4* __restrict__ sea,
                               const int* __restrict__ pos,   // pos[i]=end; start=pos[i-1]
                               const float* __restrict__ We_l,
                               const float* __restrict__ be_l,
                               float* __restrict__ h) {
    __shared__ float sWe[EDGE_CH * HIDDEN];
    __shared__ float sbe[HIDDEN];
    for (int i = threadIdx.x; i < EDGE_CH * HIDDEN; i += blockDim.x) sWe[i] = We_l[i];
    if (threadIdx.x < HIDDEN) sbe[threadIdx.x] = be_l[threadIdx.x];
    __syncthreads();

    int t = blockIdx.x * blockDim.x + threadIdx.x;
    int node = t >> 5;
    int c4 = t & 31;
    if (node >= N_NODES) return;

    int start = (node == 0) ? 0 : pos[node - 1];
    int end = pos[node];

    float4 w0 = ((const float4*)sWe)[0 * 32 + c4];
    float4 w1 = ((const float4*)sWe)[1 * 32 + c4];
    float4 w2 = ((const float4*)sWe)[2 * 32 + c4];
    float4 w3 = ((const float4*)sWe)[3 * 32 + c4];
    float4 bb = ((const float4*)sbe)[c4];

    float4 acc = make_float4(0.f, 0.f, 0.f, 0.f);
    int j = start;
    if (j < end) {
        int s0 = ssrc[j];
        float4 ea0 = sea[j];
        for (; j + 1 < end; j++) {
            int s1 = ssrc[j + 1];
            float4 ea1 = sea[j + 1];
            float4 xv = ((const float4*)(x + (size_t)s0 * HIDDEN))[c4];
            float m0 = xv.x + ea0.x*w0.x + ea0.y*w1.x + ea0.z*w2.x + ea0.w*w3.x + bb.x;
            float m1 = xv.y + ea0.x*w0.y + ea0.y*w1.y + ea0.z*w2.y + ea0.w*w3.y + bb.y;
            float m2 = xv.z + ea0.x*w0.z + ea0.y*w1.z + ea0.z*w2.z + ea0.w*w3.z + bb.z;
            float m3 = xv.w + ea0.x*w0.w + ea0.y*w1.w + ea0.z*w2.w + ea0.w*w3.w + bb.w;
            acc.x += fmaxf(m0, 0.f); acc.y += fmaxf(m1, 0.f);
            acc.z += fmaxf(m2, 0.f); acc.w += fmaxf(m3, 0.f);
            s0 = s1; ea0 = ea1;
        }
        float4 xv = ((const float4*)(x + (size_t)s0 * HIDDEN))[c4];
        float m0 = xv.x + ea0.x*w0.x + ea0.y*w1.x + ea0.z*w2.x + ea0.w*w3.x + bb.x;
        float m1 = xv.y + ea0.x*w0.y + ea0.y*w1.y + ea0.z*w2.y + ea0.w*w3.y + bb.y;
        float m2 = xv.z + ea0.x*w0.z + ea0.y*w1.z + ea0.z*w2.z + ea0.w*w3.z + bb.z;
        float m3 = xv.w + ea0.x*w0.w + ea0.y*w1.w + ea0.z*w2.w + ea0.w*w3.w + bb.w;
        acc.x += fmaxf(m0, 0.f); acc.y += fmaxf(m1, 0.f);
        acc.z += fmaxf(m2, 0.f); acc.w += fmaxf(m3, 0.f);
    }
    float4 xi = ((const float4*)(x + (size_t)node * HIDDEN))[c4];
    acc.x += xi.x; acc.y += xi.y; acc.z += xi.z; acc.w += xi.w;
    ((float4*)(h + (size_t)node * HIDDEN))[c4] = acc;
}

// fp16-shadow gather v4 (gather5): gather3's half-wave-per-node mapping and
// packed-fp16 math, with a 2-deep x-load pipeline — two independent random
// row reads in flight per wave instruction stream (round-9 showed resident-
// wave concurrency is capped; per-wave ILP is the only remaining axis).
// Accumulation order (j, then j+1) is identical to gather3.
__global__ void gather5_kernel(const __half* __restrict__ xh,
                               const int* __restrict__ ssrc,
                               const uint2* __restrict__ seah,
                               const int* __restrict__ pos,   // pos[i]=end; start=pos[i-1]
                               const float* __restrict__ We_l,
                               const float* __restrict__ be_l,
                               __half* __restrict__ h) {
    __shared__ float sWe[EDGE_CH * HIDDEN];
    __shared__ float sbe[HIDDEN];
    for (int i = threadIdx.x; i < EDGE_CH * HIDDEN; i += blockDim.x) sWe[i] = We_l[i];
    if (threadIdx.x < HIDDEN) sbe[threadIdx.x] = be_l[threadIdx.x];
    __syncthreads();

    int t = blockIdx.x * blockDim.x + threadIdx.x;
    int node = t >> 5;
    int c4 = t & 31;
    if (node >= N_NODES) return;

    int start = (node == 0) ? 0 : pos[node - 1];
    int end = pos[node];

    float4 w0 = ((const float4*)sWe)[0 * 32 + c4];
    float4 w1 = ((const float4*)sWe)[1 * 32 + c4];
    float4 w2 = ((const float4*)sWe)[2 * 32 + c4];
    float4 w3 = ((const float4*)sWe)[3 * 32 + c4];
    float4 bb = ((const float4*)sbe)[c4];

    // per-lane fp16 weight/bias registers (converted once)
    __half2 w0l = __floats2half2_rn(w0.x, w0.y), w0h = __floats2half2_rn(w0.z, w0.w);
    __half2 w1l = __floats2half2_rn(w1.x, w1.y), w1h = __floats2half2_rn(w1.z, w1.w);
    __half2 w2l = __floats2half2_rn(w2.x, w2.y), w2h = __floats2half2_rn(w2.z, w2.w);
    __half2 w3l = __floats2half2_rn(w3.x, w3.y), w3h = __floats2half2_rn(w3.z, w3.w);
    __half2 bbl = __floats2half2_rn(bb.x, bb.y), bbh = __floats2half2_rn(bb.z, bb.w);

    // self-row read issued early; overlaps the entire edge loop
    uint2 xiu = ((const uint2*)(xh + (size_t)node * HIDDEN))[c4];

    float4 acc = make_float4(0.f, 0.f, 0.f, 0.f);

#define GACCH(xu, eu) do {                                                      \
        __half2 xl  = *reinterpret_cast<const __half2*>(&(xu).x);               \
        __half2 xh2 = *reinterpret_cast<const __half2*>(&(xu).y);               \
        __half2 ea01 = *reinterpret_cast<const __half2*>(&(eu).x);              \
        __half2 ea23 = *reinterpret_cast<const __half2*>(&(eu).y);              \
        __half2 e0 = __half2half2(__low2half(ea01));                            \
        __half2 e1 = __half2half2(__high2half(ea01));                           \
        __half2 e2 = __half2half2(__low2half(ea23));                            \
        __half2 e3 = __half2half2(__high2half(ea23));                           \
        __half2 ml = __hadd2(xl, bbl);                                          \
        __half2 mh = __hadd2(xh2, bbh);                                         \
        ml = __hfma2(e0, w0l, ml); mh = __hfma2(e0, w0h, mh);                   \
        ml = __hfma2(e1, w1l, ml); mh = __hfma2(e1, w1h, mh);                   \
        ml = __hfma2(e2, w2l, ml); mh = __hfma2(e2, w2h, mh);                   \
        ml = __hfma2(e3, w3l, ml); mh = __hfma2(e3, w3h, mh);                   \
        ml = pkmax0(ml); mh = pkmax0(mh);                                       \
        float2 f0 = __half22float2(ml), f1 = __half22float2(mh);                \
        acc.x += f0.x; acc.y += f0.y; acc.z += f1.x; acc.w += f1.y;             \
    } while (0)

    int j = start;
    if (j + 1 < end) {
        int s0 = ssrc[j],        s1 = ssrc[j + 1];
        uint2 ea0 = seah[j],     ea1 = seah[j + 1];
        for (; j + 3 < end; j += 2) {
            // two independent random-row loads in flight
            uint2 xu0 = ((const uint2*)(xh + (size_t)s0 * HIDDEN))[c4];
            uint2 xu1 = ((const uint2*)(xh + (size_t)s1 * HIDDEN))[c4];
            int   t0  = ssrc[j + 2],  t1  = ssrc[j + 3];     // prefetch next pair
            uint2 eb0 = seah[j + 2],  eb1 = seah[j + 3];
            GACCH(xu0, ea0);
            GACCH(xu1, ea1);
            s0 = t0; s1 = t1; ea0 = eb0; ea1 = eb1;
        }
        uint2 xu0 = ((const uint2*)(xh + (size_t)s0 * HIDDEN))[c4];
        uint2 xu1 = ((const uint2*)(xh + (size_t)s1 * HIDDEN))[c4];
        GACCH(xu0, ea0);
        GACCH(xu1, ea1);
        j += 2;
    }
    if (j < end) {                                           // 0 or 1 left
        int s2 = ssrc[j];
        uint2 ea2 = seah[j];
        uint2 xu = ((const uint2*)(xh + (size_t)s2 * HIDDEN))[c4];
        GACCH(xu, ea2);
    }
#undef GACCH

    float4 xi = h8tof4(xiu);
    acc.x += xi.x; acc.y += xi.y; acc.z += xi.z; acc.w += xi.w;
    ((uint2*)(h + (size_t)node * HIDDEN))[c4] = f4toh8(acc);
}

// ---------------- Level C fallback: atomics ----------------

__global__ void edge_kernel(const float* __restrict__ x,
                            const float* __restrict__ edge_attr,
                            const int* __restrict__ src,
                            const int* __restrict__ dst,
                            const float* __restrict__ We_l,
                            const float* __restrict__ be_l,
                            float* __restrict__ agg) {
    __shared__ float sWe[EDGE_CH * HIDDEN];
    __shared__ float sbe[HIDDEN];
    for (int i = threadIdx.x; i < EDGE_CH * HIDDEN; i += blockDim.x) sWe[i] = We_l[i];
    if (threadIdx.x < HIDDEN) sbe[threadIdx.x] = be_l[threadIdx.x];
    __syncthreads();

    int t = blockIdx.x * blockDim.x + threadIdx.x;
    int e = t >> 5;
    if (e >= N_EDGES) return;
    int c4 = t & 31;

    int s = src[e];
    int d = dst[e];
    float4 ea = ((const float4*)edge_attr)[e];
    float4 w0 = ((const float4*)sWe)[0 * 32 + c4];
    float4 w1 = ((const float4*)sWe)[1 * 32 + c4];
    float4 w2 = ((const float4*)sWe)[2 * 32 + c4];
    float4 w3 = ((const float4*)sWe)[3 * 32 + c4];
    float4 bb = ((const float4*)sbe)[c4];
    float4 xv = ((const float4*)(x + (size_t)s * HIDDEN))[c4];

    float m0 = xv.x + ea.x*w0.x + ea.y*w1.x + ea.z*w2.x + ea.w*w3.x + bb.x;
    float m1 = xv.y + ea.x*w0.y + ea.y*w1.y + ea.z*w2.y + ea.w*w3.y + bb.y;
    float m2 = xv.z + ea.x*w0.z + ea.y*w1.z + ea.z*w2.z + ea.w*w3.z + bb.z;
    float m3 = xv.w + ea.x*w0.w + ea.y*w1.w + ea.z*w2.w + ea.w*w3.w + bb.w;

    float* ap = agg + (size_t)d * HIDDEN + c4 * 4;
    atomicAdd(ap + 0, fmaxf(m0, 0.f));
    atomicAdd(ap + 1, fmaxf(m1, 0.f));
    atomicAdd(ap + 2, fmaxf(m2, 0.f));
    atomicAdd(ap + 3, fmaxf(m3, 0.f));
}

// ---------------- host ----------------

extern "C" void kernel_launch(void* const* d_in, const int* in_sizes, int n_in,
                              void* d_out, int out_size, void* d_ws, size_t ws_size,
                              hipStream_t stream) {
    const float* emb       = (const float*)d_in[0];
    const float* We        = (const float*)d_in[1];
    const float* be        = (const float*)d_in[2];
    const float* W1        = (const float*)d_in[3];
    const float* b1        = (const float*)d_in[4];
    const float* W2        = (const float*)d_in[5];
    const float* b2        = (const float*)d_in[6];
    const float* edge_attr = (const float*)d_in[7];
    const int*   z         = (const int*)d_in[8];
    const int*   ei        = (const int*)d_in[9];
    const int*   bv        = (const int*)d_in[10];

    float* x   = (float*)d_out;
    float* agg = (float*)d_ws;
    const int* src = ei;
    const int* dst = ei + N_EDGES;

    const size_t AGG_BYTES  = (size_t)N_NODES * HIDDEN * sizeof(float);     // 51.2 MB
    const size_t POS_BYTES  = (size_t)N_NODES * sizeof(int);                // 0.4 MB
    const size_t SRC_BYTES  = (size_t)N_EDGES * sizeof(int);                // 2.4 MB
    const size_t EA_BYTES   = (size_t)N_EDGES * 4 * sizeof(float);          // 9.6 MB
    const size_t BSUM_BYTES = ((size_t)SCAN_GRID * sizeof(int) + 15) & ~15; // 1568 B
    const size_t WT_ELEMS   = (size_t)NUM_LAYERS * 2 * HIDDEN * HIDDEN;     // 98304
    const size_t WT_BYTES   = WT_ELEMS * sizeof(unsigned short);            // 196608 B
    const size_t XH_BYTES   = (size_t)N_NODES * HIDDEN * sizeof(__half);    // 25.6 MB

    const size_t OFF_POS  = AGG_BYTES;
    const size_t OFF_SRC  = OFF_POS + POS_BYTES;
    const size_t OFF_EA   = OFF_SRC + SRC_BYTES;
    const size_t OFF_BSUM = OFF_EA + EA_BYTES;
    const size_t OFF_WT   = OFF_BSUM + BSUM_BYTES;
    const size_t OFF_XH   = OFF_WT + WT_BYTES;
    const size_t TOTAL    = OFF_WT + WT_BYTES;
    const size_t TOTAL2   = OFF_XH + XH_BYTES;

    const int MLP_GRID = (N_NODES + MLP_ROWS - 1) / MLP_ROWS;

    if (ws_size >= OFF_BSUM + BSUM_BYTES) {
        // Level A: de-indirected CSR + parallel scan
        int*    pos  = (int*)((char*)d_ws + OFF_POS);
        int*    ssrc = (int*)((char*)d_ws + OFF_SRC);
        float4* sea  = (float4*)((char*)d_ws + OFF_EA);
        uint2*  seah = (uint2*)((char*)d_ws + OFF_EA);
        int*    bsum = (int*)((char*)d_ws + OFF_BSUM);
        const bool mfma  = (ws_size >= TOTAL);
        const bool halfx = (ws_size >= TOTAL2);
        unsigned short* wt = (unsigned short*)((char*)d_ws + OFF_WT);
        __half* xh = (__half*)((char*)d_ws + OFF_XH);

        // fused setup: embed (x or xh) + pos zero + batch_out + wprep
        setup_kernel<<<EMB_BLOCKS + ZB_BLOCKS + WP_BLOCKS, 256, 0, stream>>>(
            emb, z, x, xh, halfx ? 1 : 0, halfx ? 0 : 1,
            pos, bv, x + (size_t)N_NODES * HIDDEN,
            W1, W2, wt, mfma ? 1 : 0);
        hist_kernel<<<(N_EDGES + 255) / 256, 256, 0, stream>>>(dst, pos);
        scan_partial_kernel<<<SCAN_GRID, SCAN_BLOCK, 0, stream>>>(pos, bsum);
        scan_base_kernel<<<1, 512, 0, stream>>>(bsum);
        scan_final_kernel<<<SCAN_GRID, SCAN_BLOCK, 0, stream>>>(pos, bsum);
        if (halfx)
            scatter3_kernel<<<(N_EDGES + 255) / 256, 256, 0, stream>>>(dst, src, edge_attr, pos, ssrc, seah);
        else
            scatter2_kernel<<<(N_EDGES + 255) / 256, 256, 0, stream>>>(dst, src, edge_attr, pos, ssrc, sea);

        for (int l = 0; l < NUM_LAYERS; l++) {
            if (halfx) {
                gather5_kernel<<<(N_NODES * 32 + 255) / 256, 256, 0, stream>>>(
                    xh, ssrc, seah, pos,
                    We + (size_t)l * EDGE_CH * HIDDEN, be + (size_t)l * HIDDEN,
                    (__half*)agg);
            } else {
                gather2_kernel<<<(N_NODES * 32 + 255) / 256, 256, 0, stream>>>(
                    x, ssrc, sea, pos,
                    We + (size_t)l * EDGE_CH * HIDDEN, be + (size_t)l * HIDDEN, agg);
            }
            if (mfma) {
                int wx  = (!halfx || l == NUM_LAYERS - 1) ? 1 : 0;
                int wxh = (halfx && l < NUM_LAYERS - 1) ? 1 : 0;
                mlp_mfma5_kernel<<<MLP5_GRID, 1024, 0, stream>>>(
                    (const void*)agg, halfx ? 1 : 0,
                    wt + (size_t)(l * 2) * HIDDEN * HIDDEN,
                    b1 + (size_t)l * HIDDEN, b2 + (size_t)l * HIDDEN, x, xh, wx, wxh);
            } else {
                mlp_kernel<<<MLP_GRID, 256, 0, stream>>>(
                    agg,
                    W1 + (size_t)l * HIDDEN * HIDDEN, b1 + (size_t)l * HIDDEN,
                    W2 + (size_t)l * HIDDEN * HIDDEN, b2 + (size_t)l * HIDDEN, x);
            }
        }
    } else {
        // Level C: atomic fallback
        embed_init_kernel<<<(N_NODES * 32) / 256, 256, 0, stream>>>(
            emb, z, x, agg, 1, (__half*)nullptr, 0, 1);
        for (int l = 0; l < NUM_LAYERS; l++) {
            edge_kernel<<<(N_EDGES * 32) / 256, 256, 0, stream>>>(
                x, edge_attr, src, dst,
                We + (size_t)l * EDGE_CH * HIDDEN, be + (size_t)l * HIDDEN, agg);
            mlp_kernel<<<MLP_GRID, 256, 0, stream>>>(
                agg,
                W1 + (size_t)l * HIDDEN * HIDDEN, b1 + (size_t)l * HIDDEN,
                W2 + (size_t)l * HIDDEN * HIDDEN, b2 + (size_t)l * HIDDEN, x);
        }
        batch_out_kernel<<<(N_NODES + 255) / 256, 256, 0, stream>>>(bv, x + (size_t)N_NODES * HIDDEN);
    }
}